// Round 1
// baseline (610.788 us; speedup 1.0000x reference)
//
#include <hip/hip_runtime.h>

typedef __attribute__((ext_vector_type(8))) short bf16x8;     // 8 bf16 in 4 VGPRs
typedef __attribute__((ext_vector_type(8))) unsigned short u16x8;
typedef __attribute__((ext_vector_type(4))) float f32x4;

__device__ __forceinline__ unsigned short f2b(float f) {      // f32 -> bf16 RNE
  unsigned int u = __builtin_bit_cast(unsigned int, f);
  u += 0x7FFFu + ((u >> 16) & 1u);
  return (unsigned short)(u >> 16);
}
__device__ __forceinline__ float b2f(unsigned short h) {
  return __builtin_bit_cast(float, ((unsigned int)h) << 16);
}

#define AS1(p) (const __attribute__((address_space(1))) void*)(p)
#define AS3(p) (__attribute__((address_space(3))) void*)(p)

// ---------------- f32 -> bf16 convert, 8 elems/thread ----------------
__global__ __launch_bounds__(256) void k_cvt(const float* __restrict__ in,
                                             unsigned short* __restrict__ out) {
  int i = blockIdx.x * 256 + threadIdx.x;
  const float4* p = (const float4*)in + (size_t)i * 2;
  float4 a = p[0], b = p[1];
  u16x8 r;
  r[0] = f2b(a.x); r[1] = f2b(a.y); r[2] = f2b(a.z); r[3] = f2b(a.w);
  r[4] = f2b(b.x); r[5] = f2b(b.y); r[6] = f2b(b.z); r[7] = f2b(b.w);
  *((u16x8*)out + i) = r;
}

// ---------------- RoPE in-place on qk buffer [4096][2560] ----------------
// pair (d, d+64) within each 128-wide head; cos[d+64]==cos[d].
__global__ __launch_bounds__(256) void k_rope(unsigned short* __restrict__ qk,
                                              const float* __restrict__ cosb,
                                              const float* __restrict__ sinb) {
  int tid = blockIdx.x * 256 + threadIdx.x;   // 4096*20*8 = 655360
  int oct = tid & 7;
  int hd  = (tid >> 3) % 20;
  int s   = (tid >> 3) / 20;
  unsigned short* p1 = qk + (size_t)s * 2560 + hd * 128 + oct * 8;
  unsigned short* p2 = p1 + 64;
  u16x8 a = *(const u16x8*)p1;
  u16x8 b = *(const u16x8*)p2;
  const float4* cp = (const float4*)(cosb + (size_t)s * 128 + oct * 8);
  const float4* sp = (const float4*)(sinb + (size_t)s * 128 + oct * 8);
  float4 c0 = cp[0], c1 = cp[1], s0 = sp[0], s1 = sp[1];
  float cs[8] = {c0.x,c0.y,c0.z,c0.w,c1.x,c1.y,c1.z,c1.w};
  float sn[8] = {s0.x,s0.y,s0.z,s0.w,s1.x,s1.y,s1.z,s1.w};
  u16x8 ra, rb;
#pragma unroll
  for (int j = 0; j < 8; ++j) {
    float av = b2f(a[j]), bv = b2f(b[j]);
    ra[j] = f2b(av * cs[j] - bv * sn[j]);
    rb[j] = f2b(bv * cs[j] + av * sn[j]);
  }
  *(u16x8*)p1 = ra;
  *(u16x8*)p2 = rb;
}

// ---------------- GEMM C[M,N] = A[M,K] @ B[N,K]^T (bf16 in, bf16/f32 out) --
// m97 structure: 128x128 tile, BK=64, 4 waves (2x2), global_load_lds w=16,
// XOR-swizzled LDS (pre-swizzled global source + swizzled ds_read, rule #21).
template <int OUTF32>
__global__ __launch_bounds__(256) void k_gemm_bt(
    const unsigned short* __restrict__ A, const unsigned short* __restrict__ B,
    void* __restrict__ C, int K, int lda, int ldb, int ldc) {
  __shared__ unsigned short As[128 * 64];
  __shared__ unsigned short Bs[128 * 64];
  const int t = threadIdx.x;
  const int lane = t & 63, w = t >> 6;
  const int wm = w >> 1, wn = w & 1;
  const int bn = blockIdx.x, bm = blockIdx.y;
  const unsigned short* Arow = A + (size_t)(bm * 128) * lda;
  const unsigned short* Brow = B + (size_t)(bn * 128) * ldb;

  f32x4 acc[4][4] = {};
  for (int kt = 0; kt < K; kt += 64) {
#pragma unroll
    for (int i = 0; i < 4; ++i) {   // stage A tile 128x64 (8 blocks of 16B/row)
      int idx = i * 256 + t;
      int r = idx >> 3, blk = idx & 7;
      int sb = blk ^ (r & 7);
      __builtin_amdgcn_global_load_lds(AS1(Arow + (size_t)r * lda + kt + sb * 8),
                                       AS3(As + (i * 256 + w * 64) * 8), 16, 0, 0);
    }
#pragma unroll
    for (int i = 0; i < 4; ++i) {   // stage B tile 128x64
      int idx = i * 256 + t;
      int r = idx >> 3, blk = idx & 7;
      int sb = blk ^ (r & 7);
      __builtin_amdgcn_global_load_lds(AS1(Brow + (size_t)r * ldb + kt + sb * 8),
                                       AS3(Bs + (i * 256 + w * 64) * 8), 16, 0, 0);
    }
    __syncthreads();
#pragma unroll
    for (int kk = 0; kk < 2; ++kk) {
      bf16x8 av[4], bv[4];
#pragma unroll
      for (int i = 0; i < 4; ++i) {
        int r = wm * 64 + i * 16 + (lane & 15);
        int off = (r * 128 + (kk * 32 + (lane >> 4) * 8) * 2) ^ ((r & 7) << 4);
        av[i] = *(const bf16x8*)((const char*)As + off);
      }
#pragma unroll
      for (int j = 0; j < 4; ++j) {
        int r = wn * 64 + j * 16 + (lane & 15);
        int off = (r * 128 + (kk * 32 + (lane >> 4) * 8) * 2) ^ ((r & 7) << 4);
        bv[j] = *(const bf16x8*)((const char*)Bs + off);
      }
#pragma unroll
      for (int i = 0; i < 4; ++i)
#pragma unroll
        for (int j = 0; j < 4; ++j)
          acc[i][j] = __builtin_amdgcn_mfma_f32_16x16x32_bf16(av[i], bv[j], acc[i][j], 0, 0, 0);
    }
    __syncthreads();
  }
  // epilogue: D layout col=lane&15, row=(lane>>4)*4+r (verified m89)
#pragma unroll
  for (int i = 0; i < 4; ++i)
#pragma unroll
    for (int j = 0; j < 4; ++j)
#pragma unroll
      for (int r = 0; r < 4; ++r) {
        int m = bm * 128 + wm * 64 + i * 16 + (lane >> 4) * 4 + r;
        int n = bn * 128 + wn * 64 + j * 16 + (lane & 15);
        float v = acc[i][j][r];
        if (OUTF32) ((float*)C)[(size_t)m * ldc + n] = v;
        else        ((unsigned short*)C)[(size_t)m * ldc + n] = f2b(v);
      }
}

// ---------------- fused causal GQA flash attention ----------------
// block = (qt, head): 64 q rows, 4 waves x 16 rows. KV tile = 64 keys.
// K tile staged [64 keys][128 d] (swizzled); V staged from vT as [128 d][64 keys].
__global__ __launch_bounds__(256) void k_attn(const unsigned short* __restrict__ qk,
                                              const unsigned short* __restrict__ vT,
                                              unsigned short* __restrict__ ctx) {
  __shared__ unsigned short Ks[64 * 128];
  __shared__ unsigned short Vs[128 * 64];
  __shared__ unsigned short Ps[4][16 * 64];
  const int qt = blockIdx.x, h = blockIdx.y, g = h >> 2;
  const int t = threadIdx.x, lane = t & 63, w = t >> 6;
  const int l15 = lane & 15, lq = lane >> 4;
  const float scale = 0.08838834764831845f;

  bf16x8 aq[4];                     // Q 16x128 in registers (A-fragments)
  {
    const unsigned short* qb =
        qk + (size_t)(qt * 64 + w * 16 + l15) * 2560 + h * 128 + lq * 8;
#pragma unroll
    for (int sl = 0; sl < 4; ++sl) aq[sl] = *(const bf16x8*)(qb + sl * 32);
  }
  f32x4 o[8] = {};
  float mrow[4] = {-1e30f, -1e30f, -1e30f, -1e30f};
  float lrow[4] = {0.f, 0.f, 0.f, 0.f};
  const int nkt = qt + 1;

  for (int kt = 0; kt < nkt; ++kt) {
#pragma unroll
    for (int i = 0; i < 4; ++i) {   // stage K: rows=keys, 16 blocks/row, swz low 3 bits
      int idx = i * 256 + t;
      int r = idx >> 4, blk = idx & 15;
      int sb = (blk & 8) | ((blk ^ r) & 7);
      __builtin_amdgcn_global_load_lds(
          AS1(qk + (size_t)(kt * 64 + r) * 2560 + 2048 + g * 128 + sb * 8),
          AS3(Ks + (i * 256 + w * 64) * 8), 16, 0, 0);
    }
#pragma unroll
    for (int i = 0; i < 4; ++i) {   // stage V^T: rows=d, 8 blocks/row
      int idx = i * 256 + t;
      int r = idx >> 3, blk = idx & 7;
      int sb = blk ^ (r & 7);
      __builtin_amdgcn_global_load_lds(
          AS1(vT + (size_t)(g * 128 + r) * 4096 + kt * 64 + sb * 8),
          AS3(Vs + (i * 256 + w * 64) * 8), 16, 0, 0);
    }
    __syncthreads();

    // ---- S = Q @ K^T (16x64 per wave) ----
    f32x4 st[4] = {};
#pragma unroll
    for (int sl = 0; sl < 4; ++sl)
#pragma unroll
      for (int nt = 0; nt < 4; ++nt) {
        int key = nt * 16 + l15;
        int off = (key * 256 + sl * 64 + lq * 16) ^ ((key & 7) << 4);
        bf16x8 bk = *(const bf16x8*)((const char*)Ks + off);
        st[nt] = __builtin_amdgcn_mfma_f32_16x16x32_bf16(aq[sl], bk, st[nt], 0, 0, 0);
      }

    // ---- scale + causal mask ----
    float sv[4][4];
    const bool lastT = (kt == qt);
#pragma unroll
    for (int nt = 0; nt < 4; ++nt)
#pragma unroll
      for (int r = 0; r < 4; ++r) {
        float x = st[nt][r] * scale;
        if (lastT && (nt * 16 + l15 > w * 16 + lq * 4 + r)) x = -1e30f;
        sv[nt][r] = x;
      }

    // ---- online softmax (rows live in 16-lane groups) ----
    float alpha[4], rs[4];
#pragma unroll
    for (int r = 0; r < 4; ++r) {
      float pm = fmaxf(fmaxf(sv[0][r], sv[1][r]), fmaxf(sv[2][r], sv[3][r]));
#pragma unroll
      for (int m = 1; m < 16; m <<= 1) pm = fmaxf(pm, __shfl_xor(pm, m));
      float mn = fmaxf(mrow[r], pm);
      alpha[r] = __expf(mrow[r] - mn);
      mrow[r] = mn;
      rs[r] = 0.f;
    }
#pragma unroll
    for (int nt = 0; nt < 4; ++nt)
#pragma unroll
      for (int r = 0; r < 4; ++r) {
        float p = __expf(sv[nt][r] - mrow[r]);
        rs[r] += p;
        int q16 = lq * 4 + r;
        int off = (q16 * 128 + (nt * 16 + l15) * 2) ^ ((q16 & 7) << 4);
        *(unsigned short*)((char*)Ps[w] + off) = f2b(p);
      }
#pragma unroll
    for (int r = 0; r < 4; ++r) {
#pragma unroll
      for (int m = 1; m < 16; m <<= 1) rs[r] += __shfl_xor(rs[r], m);
      lrow[r] = lrow[r] * alpha[r] + rs[r];
    }
#pragma unroll
    for (int dt = 0; dt < 8; ++dt)
#pragma unroll
      for (int r = 0; r < 4; ++r) o[dt][r] *= alpha[r];

    asm volatile("s_waitcnt lgkmcnt(0)" ::: "memory");  // P writes visible (same wave)

    // ---- O += P @ V ----
#pragma unroll
    for (int ks = 0; ks < 2; ++ks) {
      int bp = (l15 * 128 + (ks * 32 + lq * 8) * 2) ^ ((l15 & 7) << 4);
      bf16x8 pa = *(const bf16x8*)((const char*)Ps[w] + bp);
#pragma unroll
      for (int dt = 0; dt < 8; ++dt) {
        int d = dt * 16 + l15;
        int off = (d * 128 + (ks * 32 + lq * 8) * 2) ^ ((d & 7) << 4);
        bf16x8 vv = *(const bf16x8*)((const char*)Vs + off);
        o[dt] = __builtin_amdgcn_mfma_f32_16x16x32_bf16(pa, vv, o[dt], 0, 0, 0);
      }
    }
    __syncthreads();
  }

  // ---- epilogue: O/l -> ctx[s][h*128+d] (bf16) ----
  float inv[4];
#pragma unroll
  for (int r = 0; r < 4; ++r) inv[r] = 1.f / lrow[r];
#pragma unroll
  for (int dt = 0; dt < 8; ++dt)
#pragma unroll
    for (int r = 0; r < 4; ++r) {
      int q = qt * 64 + w * 16 + lq * 4 + r;
      int c = h * 128 + dt * 16 + l15;
      ctx[(size_t)q * 2048 + c] = f2b(o[dt][r] * inv[r]);
    }
}

// ---------------- host ----------------
extern "C" void kernel_launch(void* const* d_in, const int* in_sizes, int n_in,
                              void* d_out, int out_size, void* d_ws, size_t ws_size,
                              hipStream_t stream) {
  const float* x    = (const float*)d_in[0];
  // d_in[1] = mask (causal, recomputed analytically)
  const float* cosb = (const float*)d_in[2];
  const float* sinb = (const float*)d_in[3];
  const float* Wq   = (const float*)d_in[4];
  const float* Wk   = (const float*)d_in[5];
  const float* Wv   = (const float*)d_in[6];
  const float* Wo   = (const float*)d_in[7];

  char* p = (char*)d_ws;
  unsigned short* xb  = (unsigned short*)p; p += (size_t)8388608 * 2;
  unsigned short* Wqb = (unsigned short*)p; p += (size_t)4194304 * 2;
  unsigned short* Wkb = (unsigned short*)p; p += (size_t)1048576 * 2;
  unsigned short* Wvb = (unsigned short*)p; p += (size_t)1048576 * 2;
  unsigned short* Wob = (unsigned short*)p; p += (size_t)4194304 * 2;
  unsigned short* qkb = (unsigned short*)p; p += (size_t)4096 * 2560 * 2;
  unsigned short* vTb = (unsigned short*)p; p += (size_t)512 * 4096 * 2;
  unsigned short* ctx = (unsigned short*)p; p += (size_t)4096 * 2048 * 2;
  if (ws_size < (size_t)(p - (char*)d_ws)) return;  // ws too small -> visible failure

  // f32 -> bf16
  k_cvt<<<4096, 256, 0, stream>>>(x,  xb);
  k_cvt<<<2048, 256, 0, stream>>>(Wq, Wqb);
  k_cvt<<< 512, 256, 0, stream>>>(Wk, Wkb);
  k_cvt<<< 512, 256, 0, stream>>>(Wv, Wvb);
  k_cvt<<<2048, 256, 0, stream>>>(Wo, Wob);

  // q = x@Wq^T (cols 0..2048 of qkb), k = x@Wk^T (cols 2048..2560)
  k_gemm_bt<0><<<dim3(16, 32), 256, 0, stream>>>(xb, Wqb, qkb,        2048, 2048, 2048, 2560);
  k_gemm_bt<0><<<dim3( 4, 32), 256, 0, stream>>>(xb, Wkb, qkb + 2048, 2048, 2048, 2048, 2560);
  // vT = Wv @ x^T  (512 x 4096) — same B^T GEMM, gives key-contiguous V
  k_gemm_bt<0><<<dim3(32,  4), 256, 0, stream>>>(Wvb, xb, vTb,        2048, 2048, 2048, 4096);

  // RoPE on q and k (20 heads of 128 cols)
  k_rope<<<2560, 256, 0, stream>>>(qkb, cosb, sinb);

  // flash attention -> ctx [4096][2048] bf16
  k_attn<<<dim3(64, 16), 256, 0, stream>>>(qkb, vTb, ctx);

  // out = ctx @ Wo^T (f32)
  k_gemm_bt<1><<<dim3(16, 32), 256, 0, stream>>>(ctx, Wob, d_out, 2048, 2048, 2048, 2048);
}

// Round 2
// 409.178 us; speedup vs baseline: 1.4927x; 1.4927x over previous
//
#include <hip/hip_runtime.h>

typedef __attribute__((ext_vector_type(8))) short bf16x8;     // 8 bf16 in 4 VGPRs
typedef __attribute__((ext_vector_type(8))) unsigned short u16x8;
typedef __attribute__((ext_vector_type(4))) float f32x4;

__device__ __forceinline__ unsigned short f2b(float f) {      // f32 -> bf16 RNE
  unsigned int u = __builtin_bit_cast(unsigned int, f);
  u += 0x7FFFu + ((u >> 16) & 1u);
  return (unsigned short)(u >> 16);
}
__device__ __forceinline__ float b2f(unsigned short h) {
  return __builtin_bit_cast(float, ((unsigned int)h) << 16);
}

#define AS1(p) (const __attribute__((address_space(1))) void*)(p)
#define AS3(p) (__attribute__((address_space(3))) void*)(p)

// ---------------- f32 -> bf16 convert, 8 elems/thread ----------------
__global__ __launch_bounds__(256) void k_cvt(const float* __restrict__ in,
                                             unsigned short* __restrict__ out) {
  int i = blockIdx.x * 256 + threadIdx.x;
  const float4* p = (const float4*)in + (size_t)i * 2;
  float4 a = p[0], b = p[1];
  u16x8 r;
  r[0] = f2b(a.x); r[1] = f2b(a.y); r[2] = f2b(a.z); r[3] = f2b(a.w);
  r[4] = f2b(b.x); r[5] = f2b(b.y); r[6] = f2b(b.z); r[7] = f2b(b.w);
  *((u16x8*)out + i) = r;
}

// ---------------- RoPE in-place on qk buffer [4096][2560] ----------------
__global__ __launch_bounds__(256) void k_rope(unsigned short* __restrict__ qk,
                                              const float* __restrict__ cosb,
                                              const float* __restrict__ sinb) {
  int tid = blockIdx.x * 256 + threadIdx.x;   // 4096*20*8 = 655360
  int oct = tid & 7;
  int hd  = (tid >> 3) % 20;
  int s   = (tid >> 3) / 20;
  unsigned short* p1 = qk + (size_t)s * 2560 + hd * 128 + oct * 8;
  unsigned short* p2 = p1 + 64;
  u16x8 a = *(const u16x8*)p1;
  u16x8 b = *(const u16x8*)p2;
  const float4* cp = (const float4*)(cosb + (size_t)s * 128 + oct * 8);
  const float4* sp = (const float4*)(sinb + (size_t)s * 128 + oct * 8);
  float4 c0 = cp[0], c1 = cp[1], s0 = sp[0], s1 = sp[1];
  float cs[8] = {c0.x,c0.y,c0.z,c0.w,c1.x,c1.y,c1.z,c1.w};
  float sn[8] = {s0.x,s0.y,s0.z,s0.w,s1.x,s1.y,s1.z,s1.w};
  u16x8 ra, rb;
#pragma unroll
  for (int j = 0; j < 8; ++j) {
    float av = b2f(a[j]), bv = b2f(b[j]);
    ra[j] = f2b(av * cs[j] - bv * sn[j]);
    rb[j] = f2b(bv * cs[j] + av * sn[j]);
  }
  *(u16x8*)p1 = ra;
  *(u16x8*)p2 = rb;
}

// ---------------- GEMM C[M,N] = A[M,K] @ B[N,K]^T (bf16 in, bf16/f32 out) --
template <int OUTF32>
__global__ __launch_bounds__(256) void k_gemm_bt(
    const unsigned short* __restrict__ A, const unsigned short* __restrict__ B,
    void* __restrict__ C, int K, int lda, int ldb, int ldc) {
  __shared__ unsigned short As[128 * 64];
  __shared__ unsigned short Bs[128 * 64];
  const int t = threadIdx.x;
  const int lane = t & 63, w = t >> 6;
  const int wm = w >> 1, wn = w & 1;
  const int bn = blockIdx.x, bm = blockIdx.y;
  const unsigned short* Arow = A + (size_t)(bm * 128) * lda;
  const unsigned short* Brow = B + (size_t)(bn * 128) * ldb;

  f32x4 acc[4][4] = {};
  for (int kt = 0; kt < K; kt += 64) {
#pragma unroll
    for (int i = 0; i < 4; ++i) {
      int idx = i * 256 + t;
      int r = idx >> 3, blk = idx & 7;
      int sb = blk ^ (r & 7);
      __builtin_amdgcn_global_load_lds(AS1(Arow + (size_t)r * lda + kt + sb * 8),
                                       AS3(As + (i * 256 + w * 64) * 8), 16, 0, 0);
    }
#pragma unroll
    for (int i = 0; i < 4; ++i) {
      int idx = i * 256 + t;
      int r = idx >> 3, blk = idx & 7;
      int sb = blk ^ (r & 7);
      __builtin_amdgcn_global_load_lds(AS1(Brow + (size_t)r * ldb + kt + sb * 8),
                                       AS3(Bs + (i * 256 + w * 64) * 8), 16, 0, 0);
    }
    __syncthreads();
#pragma unroll
    for (int kk = 0; kk < 2; ++kk) {
      bf16x8 av[4], bv[4];
#pragma unroll
      for (int i = 0; i < 4; ++i) {
        int r = wm * 64 + i * 16 + (lane & 15);
        int off = (r * 128 + (kk * 32 + (lane >> 4) * 8) * 2) ^ ((r & 7) << 4);
        av[i] = *(const bf16x8*)((const char*)As + off);
      }
#pragma unroll
      for (int j = 0; j < 4; ++j) {
        int r = wn * 64 + j * 16 + (lane & 15);
        int off = (r * 128 + (kk * 32 + (lane >> 4) * 8) * 2) ^ ((r & 7) << 4);
        bv[j] = *(const bf16x8*)((const char*)Bs + off);
      }
#pragma unroll
      for (int i = 0; i < 4; ++i)
#pragma unroll
        for (int j = 0; j < 4; ++j)
          acc[i][j] = __builtin_amdgcn_mfma_f32_16x16x32_bf16(av[i], bv[j], acc[i][j], 0, 0, 0);
    }
    __syncthreads();
  }
#pragma unroll
  for (int i = 0; i < 4; ++i)
#pragma unroll
    for (int j = 0; j < 4; ++j)
#pragma unroll
      for (int r = 0; r < 4; ++r) {
        int m = bm * 128 + wm * 64 + i * 16 + (lane >> 4) * 4 + r;
        int n = bn * 128 + wn * 64 + j * 16 + (lane & 15);
        float v = acc[i][j][r];
        if (OUTF32) ((float*)C)[(size_t)m * ldc + n] = v;
        else        ((unsigned short*)C)[(size_t)m * ldc + n] = f2b(v);
      }
}

// ---------------- attention staging helpers ----------------
__device__ __forceinline__ void stage_k(const unsigned short* __restrict__ qk,
                                        unsigned short* __restrict__ dst,
                                        int kt, int g, int t, int w) {
#pragma unroll
  for (int i = 0; i < 4; ++i) {   // K tile [64 keys][128 d], swz low 3 bits of col16
    int idx = i * 256 + t;
    int r = idx >> 4, blk = idx & 15;
    int sb = (blk & 8) | ((blk ^ r) & 7);
    __builtin_amdgcn_global_load_lds(
        AS1(qk + (size_t)(kt * 64 + r) * 2560 + 2048 + g * 128 + sb * 8),
        AS3(dst + (i * 256 + w * 64) * 8), 16, 0, 0);
  }
}
__device__ __forceinline__ void stage_v(const unsigned short* __restrict__ vT,
                                        unsigned short* __restrict__ dst,
                                        int kt, int g, int t, int w) {
#pragma unroll
  for (int i = 0; i < 4; ++i) {   // V^T tile [128 d][64 keys]
    int idx = i * 256 + t;
    int r = idx >> 3, blk = idx & 7;
    int sb = blk ^ (r & 7);
    __builtin_amdgcn_global_load_lds(
        AS1(vT + (size_t)(g * 128 + r) * 4096 + kt * 64 + sb * 8),
        AS3(dst + (i * 256 + w * 64) * 8), 16, 0, 0);
  }
}

// ---------------- fused causal GQA flash attention ----------------
// LPT order (longest qt first), double-buffered K/V prefetch with raw
// barriers + counted drain, no-max streaming softmax (scores bounded).
__global__ __launch_bounds__(256) void k_attn(const unsigned short* __restrict__ qk,
                                              const unsigned short* __restrict__ vT,
                                              unsigned short* __restrict__ ctx) {
  __shared__ unsigned short Ks[2][64 * 128];
  __shared__ unsigned short Vs[2][64 * 128];
  __shared__ unsigned short Ps[4][16 * 64];
  const int qt = (int)gridDim.x - 1 - (int)blockIdx.x;   // LPT: long blocks first
  const int h = blockIdx.y, g = h >> 2;
  const int t = threadIdx.x, lane = t & 63, w = t >> 6;
  const int l15 = lane & 15, lq = lane >> 4;
  const float SC = 0.12751741f;   // (1/sqrt(128)) * log2(e)

  bf16x8 aq[4];                   // Q 16x128 in registers (A-fragments)
  {
    const unsigned short* qb =
        qk + (size_t)(qt * 64 + w * 16 + l15) * 2560 + h * 128 + lq * 8;
#pragma unroll
    for (int sl = 0; sl < 4; ++sl) aq[sl] = *(const bf16x8*)(qb + sl * 32);
  }
  f32x4 o[8] = {};
  float lrow[4] = {0.f, 0.f, 0.f, 0.f};
  const int nkt = qt + 1;

  stage_k(qk, Ks[0], 0, g, t, w);
  stage_v(vT, Vs[0], 0, g, t, w);
  asm volatile("s_waitcnt vmcnt(0)" ::: "memory");
  __builtin_amdgcn_s_barrier();

  for (int kt = 0; kt < nkt; ++kt) {
    const int cur = kt & 1;
    const unsigned short* Kb = Ks[cur];
    const unsigned short* Vb = Vs[cur];
    if (kt + 1 < nkt) {           // prefetch next tile into other buffer
      stage_k(qk, Ks[cur ^ 1], kt + 1, g, t, w);
      stage_v(vT, Vs[cur ^ 1], kt + 1, g, t, w);
    }

    // ---- S = Q @ K^T (16x64 per wave) ----
    f32x4 st[4] = {};
    __builtin_amdgcn_s_setprio(1);
#pragma unroll
    for (int sl = 0; sl < 4; ++sl)
#pragma unroll
      for (int nt = 0; nt < 4; ++nt) {
        int key = nt * 16 + l15;
        int off = (key * 256 + sl * 64 + lq * 16) ^ ((key & 7) << 4);
        bf16x8 bk = *(const bf16x8*)((const char*)Kb + off);
        st[nt] = __builtin_amdgcn_mfma_f32_16x16x32_bf16(aq[sl], bk, st[nt], 0, 0, 0);
      }
    __builtin_amdgcn_s_setprio(0);

    // ---- streaming softmax, no max-tracking (scores bounded ~ +-8) ----
    const bool lastT = (kt == qt);
#pragma unroll
    for (int nt = 0; nt < 4; ++nt)
#pragma unroll
      for (int r = 0; r < 4; ++r) {
        float x = st[nt][r] * SC;
        if (lastT && (nt * 16 + l15 > w * 16 + lq * 4 + r)) x = -1e30f;
        float p = __builtin_amdgcn_exp2f(x);
        unsigned short pb = f2b(p);
        lrow[r] += b2f(pb);       // accumulate exactly what PV consumes
        int q16 = lq * 4 + r;
        int off = (q16 * 128 + (nt * 16 + l15) * 2) ^ ((q16 & 7) << 4);
        *(unsigned short*)((char*)Ps[w] + off) = pb;
      }
    asm volatile("s_waitcnt lgkmcnt(0)" ::: "memory");  // P visible (same wave)

    // ---- O += P @ V ----
    __builtin_amdgcn_s_setprio(1);
#pragma unroll
    for (int ks = 0; ks < 2; ++ks) {
      int bp = (l15 * 128 + (ks * 32 + lq * 8) * 2) ^ ((l15 & 7) << 4);
      bf16x8 pa = *(const bf16x8*)((const char*)Ps[w] + bp);
#pragma unroll
      for (int dt = 0; dt < 8; ++dt) {
        int d = dt * 16 + l15;
        int off = (d * 128 + (ks * 32 + lq * 8) * 2) ^ ((d & 7) << 4);
        bf16x8 vv = *(const bf16x8*)((const char*)Vb + off);
        o[dt] = __builtin_amdgcn_mfma_f32_16x16x32_bf16(pa, vv, o[dt], 0, 0, 0);
      }
    }
    __builtin_amdgcn_s_setprio(0);

    // drain prefetch (hidden under this tile's compute) + tile boundary
    asm volatile("s_waitcnt vmcnt(0)" ::: "memory");
    __builtin_amdgcn_s_barrier();
  }

  // ---- epilogue: reduce row sums across 16 lanes, normalize, store ----
  float inv[4];
#pragma unroll
  for (int r = 0; r < 4; ++r) {
    float s = lrow[r];
#pragma unroll
    for (int m = 1; m < 16; m <<= 1) s += __shfl_xor(s, m);
    inv[r] = 1.f / s;
  }
#pragma unroll
  for (int dt = 0; dt < 8; ++dt)
#pragma unroll
    for (int r = 0; r < 4; ++r) {
      int q = qt * 64 + w * 16 + lq * 4 + r;
      int c = h * 128 + dt * 16 + l15;
      ctx[(size_t)q * 2048 + c] = f2b(o[dt][r] * inv[r]);
    }
}

// ---------------- host ----------------
extern "C" void kernel_launch(void* const* d_in, const int* in_sizes, int n_in,
                              void* d_out, int out_size, void* d_ws, size_t ws_size,
                              hipStream_t stream) {
  const float* x    = (const float*)d_in[0];
  const float* cosb = (const float*)d_in[2];
  const float* sinb = (const float*)d_in[3];
  const float* Wq   = (const float*)d_in[4];
  const float* Wk   = (const float*)d_in[5];
  const float* Wv   = (const float*)d_in[6];
  const float* Wo   = (const float*)d_in[7];

  char* p = (char*)d_ws;
  unsigned short* xb  = (unsigned short*)p; p += (size_t)8388608 * 2;
  unsigned short* Wqb = (unsigned short*)p; p += (size_t)4194304 * 2;
  unsigned short* Wkb = (unsigned short*)p; p += (size_t)1048576 * 2;
  unsigned short* Wvb = (unsigned short*)p; p += (size_t)1048576 * 2;
  unsigned short* Wob = (unsigned short*)p; p += (size_t)4194304 * 2;
  unsigned short* qkb = (unsigned short*)p; p += (size_t)4096 * 2560 * 2;
  unsigned short* vTb = (unsigned short*)p; p += (size_t)512 * 4096 * 2;
  unsigned short* ctx = (unsigned short*)p; p += (size_t)4096 * 2048 * 2;
  if (ws_size < (size_t)(p - (char*)d_ws)) return;

  k_cvt<<<4096, 256, 0, stream>>>(x,  xb);
  k_cvt<<<2048, 256, 0, stream>>>(Wq, Wqb);
  k_cvt<<< 512, 256, 0, stream>>>(Wk, Wkb);
  k_cvt<<< 512, 256, 0, stream>>>(Wv, Wvb);
  k_cvt<<<2048, 256, 0, stream>>>(Wo, Wob);

  k_gemm_bt<0><<<dim3(16, 32), 256, 0, stream>>>(xb, Wqb, qkb,        2048, 2048, 2048, 2560);
  k_gemm_bt<0><<<dim3( 4, 32), 256, 0, stream>>>(xb, Wkb, qkb + 2048, 2048, 2048, 2048, 2560);
  k_gemm_bt<0><<<dim3(32,  4), 256, 0, stream>>>(Wvb, xb, vTb,        2048, 2048, 2048, 4096);

  k_rope<<<2560, 256, 0, stream>>>(qkb, cosb, sinb);

  k_attn<<<dim3(64, 16), 256, 0, stream>>>(qkb, vTb, ctx);

  k_gemm_bt<1><<<dim3(16, 32), 256, 0, stream>>>(ctx, Wob, d_out, 2048, 2048, 2048, 2048);
}

// Round 3
// 310.022 us; speedup vs baseline: 1.9701x; 1.3198x over previous
//
#include <hip/hip_runtime.h>

typedef __attribute__((ext_vector_type(8))) short bf16x8;     // 8 bf16 in 4 VGPRs
typedef __attribute__((ext_vector_type(4))) short bf16x4;     // 4 bf16 in 2 VGPRs
typedef __attribute__((ext_vector_type(8))) unsigned short u16x8;
typedef __attribute__((ext_vector_type(4))) float f32x4;

__device__ __forceinline__ unsigned short f2b(float f) {      // f32 -> bf16 RNE
  unsigned int u = __builtin_bit_cast(unsigned int, f);
  u += 0x7FFFu + ((u >> 16) & 1u);
  return (unsigned short)(u >> 16);
}
__device__ __forceinline__ float b2f(unsigned short h) {
  return __builtin_bit_cast(float, ((unsigned int)h) << 16);
}

__device__ __forceinline__ f32x4 mfma16x16x16(bf16x4 a, bf16x4 b, f32x4 c) {
#if __has_builtin(__builtin_amdgcn_mfma_f32_16x16x16bf16_1k)
  return __builtin_amdgcn_mfma_f32_16x16x16bf16_1k(a, b, c, 0, 0, 0);
#else
  asm volatile("v_mfma_f32_16x16x16_bf16 %0, %1, %2, %0" : "+v"(c) : "v"(a), "v"(b));
  return c;
#endif
}

#define AS1(p) (const __attribute__((address_space(1))) void*)(p)
#define AS3(p) (__attribute__((address_space(3))) void*)(p)

// ---------------- f32 -> bf16 convert, 8 elems/thread ----------------
__global__ __launch_bounds__(256) void k_cvt(const float* __restrict__ in,
                                             unsigned short* __restrict__ out) {
  int i = blockIdx.x * 256 + threadIdx.x;
  const float4* p = (const float4*)in + (size_t)i * 2;
  float4 a = p[0], b = p[1];
  u16x8 r;
  r[0] = f2b(a.x); r[1] = f2b(a.y); r[2] = f2b(a.z); r[3] = f2b(a.w);
  r[4] = f2b(b.x); r[5] = f2b(b.y); r[6] = f2b(b.z); r[7] = f2b(b.w);
  *((u16x8*)out + i) = r;
}

// ---------------- RoPE in-place on qk buffer [4096][2560] ----------------
__global__ __launch_bounds__(256) void k_rope(unsigned short* __restrict__ qk,
                                              const float* __restrict__ cosb,
                                              const float* __restrict__ sinb) {
  int tid = blockIdx.x * 256 + threadIdx.x;   // 4096*20*8 = 655360
  int oct = tid & 7;
  int hd  = (tid >> 3) % 20;
  int s   = (tid >> 3) / 20;
  unsigned short* p1 = qk + (size_t)s * 2560 + hd * 128 + oct * 8;
  unsigned short* p2 = p1 + 64;
  u16x8 a = *(const u16x8*)p1;
  u16x8 b = *(const u16x8*)p2;
  const float4* cp = (const float4*)(cosb + (size_t)s * 128 + oct * 8);
  const float4* sp = (const float4*)(sinb + (size_t)s * 128 + oct * 8);
  float4 c0 = cp[0], c1 = cp[1], s0 = sp[0], s1 = sp[1];
  float cs[8] = {c0.x,c0.y,c0.z,c0.w,c1.x,c1.y,c1.z,c1.w};
  float sn[8] = {s0.x,s0.y,s0.z,s0.w,s1.x,s1.y,s1.z,s1.w};
  u16x8 ra, rb;
#pragma unroll
  for (int j = 0; j < 8; ++j) {
    float av = b2f(a[j]), bv = b2f(b[j]);
    ra[j] = f2b(av * cs[j] - bv * sn[j]);
    rb[j] = f2b(bv * cs[j] + av * sn[j]);
  }
  *(u16x8*)p1 = ra;
  *(u16x8*)p2 = rb;
}

// ---------------- GEMM C[M,N] = A[M,K] @ B[N,K]^T (bf16 in, bf16/f32 out) --
template <int OUTF32>
__global__ __launch_bounds__(256) void k_gemm_bt(
    const unsigned short* __restrict__ A, const unsigned short* __restrict__ B,
    void* __restrict__ C, int K, int lda, int ldb, int ldc) {
  __shared__ unsigned short As[128 * 64];
  __shared__ unsigned short Bs[128 * 64];
  const int t = threadIdx.x;
  const int lane = t & 63, w = t >> 6;
  const int wm = w >> 1, wn = w & 1;
  const int bn = blockIdx.x, bm = blockIdx.y;
  const unsigned short* Arow = A + (size_t)(bm * 128) * lda;
  const unsigned short* Brow = B + (size_t)(bn * 128) * ldb;

  f32x4 acc[4][4] = {};
  for (int kt = 0; kt < K; kt += 64) {
#pragma unroll
    for (int i = 0; i < 4; ++i) {
      int idx = i * 256 + t;
      int r = idx >> 3, blk = idx & 7;
      int sb = blk ^ (r & 7);
      __builtin_amdgcn_global_load_lds(AS1(Arow + (size_t)r * lda + kt + sb * 8),
                                       AS3(As + (i * 256 + w * 64) * 8), 16, 0, 0);
    }
#pragma unroll
    for (int i = 0; i < 4; ++i) {
      int idx = i * 256 + t;
      int r = idx >> 3, blk = idx & 7;
      int sb = blk ^ (r & 7);
      __builtin_amdgcn_global_load_lds(AS1(Brow + (size_t)r * ldb + kt + sb * 8),
                                       AS3(Bs + (i * 256 + w * 64) * 8), 16, 0, 0);
    }
    __syncthreads();
#pragma unroll
    for (int kk = 0; kk < 2; ++kk) {
      bf16x8 av[4], bv[4];
#pragma unroll
      for (int i = 0; i < 4; ++i) {
        int r = wm * 64 + i * 16 + (lane & 15);
        int off = (r * 128 + (kk * 32 + (lane >> 4) * 8) * 2) ^ ((r & 7) << 4);
        av[i] = *(const bf16x8*)((const char*)As + off);
      }
#pragma unroll
      for (int j = 0; j < 4; ++j) {
        int r = wn * 64 + j * 16 + (lane & 15);
        int off = (r * 128 + (kk * 32 + (lane >> 4) * 8) * 2) ^ ((r & 7) << 4);
        bv[j] = *(const bf16x8*)((const char*)Bs + off);
      }
#pragma unroll
      for (int i = 0; i < 4; ++i)
#pragma unroll
        for (int j = 0; j < 4; ++j)
          acc[i][j] = __builtin_amdgcn_mfma_f32_16x16x32_bf16(av[i], bv[j], acc[i][j], 0, 0, 0);
    }
    __syncthreads();
  }
#pragma unroll
  for (int i = 0; i < 4; ++i)
#pragma unroll
    for (int j = 0; j < 4; ++j)
#pragma unroll
      for (int r = 0; r < 4; ++r) {
        int m = bm * 128 + wm * 64 + i * 16 + (lane >> 4) * 4 + r;
        int n = bn * 128 + wn * 64 + j * 16 + (lane & 15);
        float v = acc[i][j][r];
        if (OUTF32) ((float*)C)[(size_t)m * ldc + n] = v;
        else        ((unsigned short*)C)[(size_t)m * ldc + n] = f2b(v);
      }
}

// ---------------- attention staging helpers ----------------
__device__ __forceinline__ void stage_k(const unsigned short* __restrict__ qk,
                                        unsigned short* __restrict__ dst,
                                        int kt, int g, int t, int w) {
#pragma unroll
  for (int i = 0; i < 4; ++i) {   // K tile [64 keys][128 d], swz low 3 bits of col16
    int idx = i * 256 + t;
    int r = idx >> 4, blk = idx & 15;
    int sb = (blk & 8) | ((blk ^ r) & 7);
    __builtin_amdgcn_global_load_lds(
        AS1(qk + (size_t)(kt * 64 + r) * 2560 + 2048 + g * 128 + sb * 8),
        AS3(dst + (i * 256 + w * 64) * 8), 16, 0, 0);
  }
}
__device__ __forceinline__ void stage_v(const unsigned short* __restrict__ vT,
                                        unsigned short* __restrict__ dst,
                                        int kt, int g, int t, int w) {
#pragma unroll
  for (int i = 0; i < 4; ++i) {   // V^T tile [128 d][64 keys]
    int idx = i * 256 + t;
    int r = idx >> 3, blk = idx & 7;
    int sb = blk ^ (r & 7);
    __builtin_amdgcn_global_load_lds(
        AS1(vT + (size_t)(g * 128 + r) * 4096 + kt * 64 + sb * 8),
        AS3(dst + (i * 256 + w * 64) * 8), 16, 0, 0);
  }
}

// ---------------- fused causal GQA flash attention ----------------
// Paired q-tiles (block b does qt=b and qt=63-b -> uniform 65 tiles/block,
// 512 blocks = exactly 2/CU resident). Swapped QK^T: st = mfma(K, Q) puts a
// full P-row slice in each lane's registers; PV consumes it directly via
// 16x16x16 MFMA (A-frag layout == D-frag layout of swapped QK). No P-LDS,
// no cross-lane ops in the loop. Double-buffered K/V prefetch, no-max
// streaming softmax (scores bounded).
__global__ __launch_bounds__(256, 2) void k_attn(const unsigned short* __restrict__ qk,
                                                 const unsigned short* __restrict__ vT,
                                                 unsigned short* __restrict__ ctx) {
  __shared__ unsigned short Ks[2][64 * 128];
  __shared__ unsigned short Vs[2][64 * 128];
  const int b = blockIdx.x, h = blockIdx.y, g = h >> 2;
  const int t = threadIdx.x, lane = t & 63, w = t >> 6;
  const int l15 = lane & 15, lq = lane >> 4;
  const float SC = 0.12751741f;   // (1/sqrt(128)) * log2(e)

  for (int ph = 0; ph < 2; ++ph) {
    const int qt = ph ? 63 - b : b;
    const int nkt = qt + 1;
    const int qg = qt * 64 + w * 16 + l15;   // this lane's softmax q-row (global)

    bf16x8 aq[4];                 // Q fragments (B-operand: col=l15, k-chunk by lq)
    {
      const unsigned short* qb =
          qk + (size_t)(qt * 64 + w * 16 + l15) * 2560 + h * 128 + lq * 8;
#pragma unroll
      for (int sl = 0; sl < 4; ++sl) aq[sl] = *(const bf16x8*)(qb + sl * 32);
    }
    f32x4 o[8] = {};
    float lsum = 0.f;

    stage_k(qk, Ks[0], 0, g, t, w);
    stage_v(vT, Vs[0], 0, g, t, w);
    asm volatile("s_waitcnt vmcnt(0)" ::: "memory");
    __builtin_amdgcn_s_barrier();

    for (int kt = 0; kt < nkt; ++kt) {
      const int cur = kt & 1;
      const unsigned short* Kb = Ks[cur];
      const unsigned short* Vb = Vs[cur];
      if (kt + 1 < nkt) {         // prefetch next tile into other buffer
        stage_k(qk, Ks[cur ^ 1], kt + 1, g, t, w);
        stage_v(vT, Vs[cur ^ 1], kt + 1, g, t, w);
      }

      // ---- S^T = K @ Q^T : lane gets P[q=l15][key=nt*16+lq*4+r] ----
      f32x4 st[4] = {};
      __builtin_amdgcn_s_setprio(1);
#pragma unroll
      for (int sl = 0; sl < 4; ++sl)
#pragma unroll
        for (int nt = 0; nt < 4; ++nt) {
          int key = nt * 16 + l15;
          int off = (key * 256 + sl * 64 + lq * 16) ^ ((key & 7) << 4);
          bf16x8 bk = *(const bf16x8*)((const char*)Kb + off);
          st[nt] = __builtin_amdgcn_mfma_f32_16x16x32_bf16(bk, aq[sl], st[nt], 0, 0, 0);
        }
      __builtin_amdgcn_s_setprio(0);

      // ---- streaming softmax, in-register (no max tracking, no cross-lane) --
      const bool lastT = (kt == qt);
      bf16x4 pa[4];
#pragma unroll
      for (int nt = 0; nt < 4; ++nt)
#pragma unroll
        for (int r = 0; r < 4; ++r) {
          float x = st[nt][r] * SC;
          int key = kt * 64 + nt * 16 + lq * 4 + r;
          float p = (lastT && key > qg) ? 0.f : __builtin_amdgcn_exp2f(x);
          unsigned short pb = f2b(p);
          lsum += b2f(pb);        // accumulate exactly what PV consumes
          pa[nt][r] = (short)pb;
        }

      // ---- O += P @ V : A = P from regs, B = V^T b64 reads ----
      __builtin_amdgcn_s_setprio(1);
#pragma unroll
      for (int nt = 0; nt < 4; ++nt)
#pragma unroll
        for (int dt = 0; dt < 8; ++dt) {
          int d = dt * 16 + l15;
          int off = (d * 128 + nt * 32 + lq * 8) ^ ((d & 7) << 4);
          bf16x4 vv = *(const bf16x4*)((const char*)Vb + off);
          o[dt] = mfma16x16x16(pa[nt], vv, o[dt]);
        }
      __builtin_amdgcn_s_setprio(0);

      // drain prefetch (hidden under this tile's compute) + tile boundary
      asm volatile("s_waitcnt vmcnt(0)" ::: "memory");
      __builtin_amdgcn_s_barrier();
    }

    // ---- epilogue: row-sum reduce (4 lq-slices), normalize, store ----
    float fs = lsum;
    fs += __shfl_xor(fs, 16);
    fs += __shfl_xor(fs, 32);     // lanes l15, l15+16, +32, +48 all hold row sum
    float invq[4];
#pragma unroll
    for (int r = 0; r < 4; ++r) invq[r] = 1.f / __shfl(fs, lq * 4 + r);
#pragma unroll
    for (int dt = 0; dt < 8; ++dt)
#pragma unroll
      for (int r = 0; r < 4; ++r) {
        int q = qt * 64 + w * 16 + lq * 4 + r;
        int c = h * 128 + dt * 16 + l15;
        ctx[(size_t)q * 2048 + c] = f2b(o[dt][r] * invq[r]);
      }
  }
}

// ---------------- host ----------------
extern "C" void kernel_launch(void* const* d_in, const int* in_sizes, int n_in,
                              void* d_out, int out_size, void* d_ws, size_t ws_size,
                              hipStream_t stream) {
  const float* x    = (const float*)d_in[0];
  const float* cosb = (const float*)d_in[2];
  const float* sinb = (const float*)d_in[3];
  const float* Wq   = (const float*)d_in[4];
  const float* Wk   = (const float*)d_in[5];
  const float* Wv   = (const float*)d_in[6];
  const float* Wo   = (const float*)d_in[7];

  char* p = (char*)d_ws;
  unsigned short* xb  = (unsigned short*)p; p += (size_t)8388608 * 2;
  unsigned short* Wqb = (unsigned short*)p; p += (size_t)4194304 * 2;
  unsigned short* Wkb = (unsigned short*)p; p += (size_t)1048576 * 2;
  unsigned short* Wvb = (unsigned short*)p; p += (size_t)1048576 * 2;
  unsigned short* Wob = (unsigned short*)p; p += (size_t)4194304 * 2;
  unsigned short* qkb = (unsigned short*)p; p += (size_t)4096 * 2560 * 2;
  unsigned short* vTb = (unsigned short*)p; p += (size_t)512 * 4096 * 2;
  unsigned short* ctx = (unsigned short*)p; p += (size_t)4096 * 2048 * 2;
  if (ws_size < (size_t)(p - (char*)d_ws)) return;

  k_cvt<<<4096, 256, 0, stream>>>(x,  xb);
  k_cvt<<<2048, 256, 0, stream>>>(Wq, Wqb);
  k_cvt<<< 512, 256, 0, stream>>>(Wk, Wkb);
  k_cvt<<< 512, 256, 0, stream>>>(Wv, Wvb);
  k_cvt<<<2048, 256, 0, stream>>>(Wo, Wob);

  k_gemm_bt<0><<<dim3(16, 32), 256, 0, stream>>>(xb, Wqb, qkb,        2048, 2048, 2048, 2560);
  k_gemm_bt<0><<<dim3( 4, 32), 256, 0, stream>>>(xb, Wkb, qkb + 2048, 2048, 2048, 2048, 2560);
  k_gemm_bt<0><<<dim3(32,  4), 256, 0, stream>>>(Wvb, xb, vTb,        2048, 2048, 2048, 4096);

  k_rope<<<2560, 256, 0, stream>>>(qkb, cosb, sinb);

  k_attn<<<dim3(32, 16), 256, 0, stream>>>(qkb, vTb, ctx);

  k_gemm_bt<1><<<dim3(16, 32), 256, 0, stream>>>(ctx, Wob, d_out, 2048, 2048, 2048, 2048);
}

// Round 4
// 255.097 us; speedup vs baseline: 2.3943x; 1.2153x over previous
//
#include <hip/hip_runtime.h>

typedef __attribute__((ext_vector_type(8))) short bf16x8;     // 8 bf16 in 4 VGPRs
typedef __attribute__((ext_vector_type(4))) short bf16x4;     // 4 bf16 in 2 VGPRs
typedef __attribute__((ext_vector_type(8))) unsigned short u16x8;
typedef __attribute__((ext_vector_type(4))) float f32x4;

__device__ __forceinline__ unsigned short f2b(float f) {      // f32 -> bf16 RNE
  unsigned int u = __builtin_bit_cast(unsigned int, f);
  u += 0x7FFFu + ((u >> 16) & 1u);
  return (unsigned short)(u >> 16);
}
__device__ __forceinline__ float b2f(unsigned short h) {
  return __builtin_bit_cast(float, ((unsigned int)h) << 16);
}

__device__ __forceinline__ f32x4 mfma16x16x16(bf16x4 a, bf16x4 b, f32x4 c) {
#if __has_builtin(__builtin_amdgcn_mfma_f32_16x16x16bf16_1k)
  return __builtin_amdgcn_mfma_f32_16x16x16bf16_1k(a, b, c, 0, 0, 0);
#else
  asm volatile("v_mfma_f32_16x16x16_bf16 %0, %1, %2, %0" : "+v"(c) : "v"(a), "v"(b));
  return c;
#endif
}

#define AS1(p) (const __attribute__((address_space(1))) void*)(p)
#define AS3(p) (__attribute__((address_space(3))) void*)(p)

// ---------------- f32 -> bf16 convert (optional scale), 8 elems/thread ------
__global__ __launch_bounds__(256) void k_cvt(const float* __restrict__ in,
                                             unsigned short* __restrict__ out,
                                             float scale) {
  int i = blockIdx.x * 256 + threadIdx.x;
  const float4* p = (const float4*)in + (size_t)i * 2;
  float4 a = p[0], b = p[1];
  u16x8 r;
  r[0] = f2b(a.x * scale); r[1] = f2b(a.y * scale);
  r[2] = f2b(a.z * scale); r[3] = f2b(a.w * scale);
  r[4] = f2b(b.x * scale); r[5] = f2b(b.y * scale);
  r[6] = f2b(b.z * scale); r[7] = f2b(b.w * scale);
  *((u16x8*)out + i) = r;
}

// ---------------- RoPE in-place on qkv buffer [4096][3072], q/k cols only ---
__global__ __launch_bounds__(256) void k_rope(unsigned short* __restrict__ qk,
                                              const float* __restrict__ cosb,
                                              const float* __restrict__ sinb) {
  int tid = blockIdx.x * 256 + threadIdx.x;   // 4096*20*8 = 655360
  int oct = tid & 7;
  int hd  = (tid >> 3) % 20;                  // heads 0..19 (q:0-15, k:16-19)
  int s   = (tid >> 3) / 20;
  unsigned short* p1 = qk + (size_t)s * 3072 + hd * 128 + oct * 8;
  unsigned short* p2 = p1 + 64;
  u16x8 a = *(const u16x8*)p1;
  u16x8 b = *(const u16x8*)p2;
  const float4* cp = (const float4*)(cosb + (size_t)s * 128 + oct * 8);
  const float4* sp = (const float4*)(sinb + (size_t)s * 128 + oct * 8);
  float4 c0 = cp[0], c1 = cp[1], s0 = sp[0], s1 = sp[1];
  float cs[8] = {c0.x,c0.y,c0.z,c0.w,c1.x,c1.y,c1.z,c1.w};
  float sn[8] = {s0.x,s0.y,s0.z,s0.w,s1.x,s1.y,s1.z,s1.w};
  u16x8 ra, rb;
#pragma unroll
  for (int j = 0; j < 8; ++j) {
    float av = b2f(a[j]), bv = b2f(b[j]);
    ra[j] = f2b(av * cs[j] - bv * sn[j]);
    rb[j] = f2b(bv * cs[j] + av * sn[j]);
  }
  *(u16x8*)p1 = ra;
  *(u16x8*)p2 = rb;
}

// ---------------- V transpose: qkv cols 2560..3071 -> vT[512][4096] ---------
__global__ __launch_bounds__(256) void k_tr(const unsigned short* __restrict__ src,
                                            unsigned short* __restrict__ dst) {
  __shared__ unsigned short tile[64][72];     // +8 pad: conflict-free gather
  const int bs = blockIdx.x, bc = blockIdx.y, t = threadIdx.x;
#pragma unroll
  for (int i = 0; i < 2; ++i) {
    int c8 = t + 256 * i;                     // 0..511
    int row = c8 >> 3, cb = c8 & 7;
    u16x8 v = *(const u16x8*)(src + (size_t)(bs * 64 + row) * 3072 + 2560 + bc * 64 + cb * 8);
#pragma unroll
    for (int j = 0; j < 8; ++j) tile[row][cb * 8 + j] = v[j];
  }
  __syncthreads();
#pragma unroll
  for (int i = 0; i < 2; ++i) {
    int c8 = t + 256 * i;
    int crow = c8 >> 3, sb = c8 & 7;
    u16x8 v;
#pragma unroll
    for (int j = 0; j < 8; ++j) v[j] = tile[sb * 8 + j][crow];
    *(u16x8*)(dst + (size_t)(bc * 64 + crow) * 4096 + bs * 64 + sb * 8) = v;
  }
}

// ---------------- GEMM C[M,N] = A[M,K] @ B[N,K]^T (bf16 in, bf16/f32 out) --
template <int OUTF32>
__global__ __launch_bounds__(256) void k_gemm_bt(
    const unsigned short* __restrict__ A, const unsigned short* __restrict__ B,
    void* __restrict__ C, int K, int lda, int ldb, int ldc) {
  __shared__ unsigned short As[128 * 64];
  __shared__ unsigned short Bs[128 * 64];
  const int t = threadIdx.x;
  const int lane = t & 63, w = t >> 6;
  const int wm = w >> 1, wn = w & 1;
  const int bn = blockIdx.x, bm = blockIdx.y;
  const unsigned short* Arow = A + (size_t)(bm * 128) * lda;
  const unsigned short* Brow = B + (size_t)(bn * 128) * ldb;

  f32x4 acc[4][4] = {};
  for (int kt = 0; kt < K; kt += 64) {
#pragma unroll
    for (int i = 0; i < 4; ++i) {
      int idx = i * 256 + t;
      int r = idx >> 3, blk = idx & 7;
      int sb = blk ^ (r & 7);
      __builtin_amdgcn_global_load_lds(AS1(Arow + (size_t)r * lda + kt + sb * 8),
                                       AS3(As + (i * 256 + w * 64) * 8), 16, 0, 0);
    }
#pragma unroll
    for (int i = 0; i < 4; ++i) {
      int idx = i * 256 + t;
      int r = idx >> 3, blk = idx & 7;
      int sb = blk ^ (r & 7);
      __builtin_amdgcn_global_load_lds(AS1(Brow + (size_t)r * ldb + kt + sb * 8),
                                       AS3(Bs + (i * 256 + w * 64) * 8), 16, 0, 0);
    }
    __syncthreads();
#pragma unroll
    for (int kk = 0; kk < 2; ++kk) {
      bf16x8 av[4], bv[4];
#pragma unroll
      for (int i = 0; i < 4; ++i) {
        int r = wm * 64 + i * 16 + (lane & 15);
        int off = (r * 128 + (kk * 32 + (lane >> 4) * 8) * 2) ^ ((r & 7) << 4);
        av[i] = *(const bf16x8*)((const char*)As + off);
      }
#pragma unroll
      for (int j = 0; j < 4; ++j) {
        int r = wn * 64 + j * 16 + (lane & 15);
        int off = (r * 128 + (kk * 32 + (lane >> 4) * 8) * 2) ^ ((r & 7) << 4);
        bv[j] = *(const bf16x8*)((const char*)Bs + off);
      }
#pragma unroll
      for (int i = 0; i < 4; ++i)
#pragma unroll
        for (int j = 0; j < 4; ++j)
          acc[i][j] = __builtin_amdgcn_mfma_f32_16x16x32_bf16(av[i], bv[j], acc[i][j], 0, 0, 0);
    }
    __syncthreads();
  }
#pragma unroll
  for (int i = 0; i < 4; ++i)
#pragma unroll
    for (int j = 0; j < 4; ++j)
#pragma unroll
      for (int r = 0; r < 4; ++r) {
        int m = bm * 128 + wm * 64 + i * 16 + (lane >> 4) * 4 + r;
        int n = bn * 128 + wn * 64 + j * 16 + (lane & 15);
        float v = acc[i][j][r];
        if (OUTF32) ((float*)C)[(size_t)m * ldc + n] = v;
        else        ((unsigned short*)C)[(size_t)m * ldc + n] = f2b(v);
      }
}

// ---------------- attention staging helpers ----------------
__device__ __forceinline__ void stage_k(const unsigned short* __restrict__ qk,
                                        unsigned short* __restrict__ dst,
                                        int kt, int g, int t, int w) {
#pragma unroll
  for (int i = 0; i < 4; ++i) {   // K tile [64 keys][128 d], swz low 3 bits of col16
    int idx = i * 256 + t;
    int r = idx >> 4, blk = idx & 15;
    int sb = (blk & 8) | ((blk ^ r) & 7);
    __builtin_amdgcn_global_load_lds(
        AS1(qk + (size_t)(kt * 64 + r) * 3072 + 2048 + g * 128 + sb * 8),
        AS3(dst + (i * 256 + w * 64) * 8), 16, 0, 0);
  }
}
__device__ __forceinline__ void stage_v(const unsigned short* __restrict__ vT,
                                        unsigned short* __restrict__ dst,
                                        int kt, int g, int t, int w) {
#pragma unroll
  for (int i = 0; i < 4; ++i) {   // V^T tile [128 d][64 keys]
    int idx = i * 256 + t;
    int r = idx >> 3, blk = idx & 7;
    int sb = blk ^ (r & 7);
    __builtin_amdgcn_global_load_lds(
        AS1(vT + (size_t)(g * 128 + r) * 4096 + kt * 64 + sb * 8),
        AS3(dst + (i * 256 + w * 64) * 8), 16, 0, 0);
  }
}

// ---------------- fused causal GQA flash attention ----------------
// Paired q-tiles, swapped QK^T (P stays in registers), register-direct PV,
// double-buffered K/V, no-max streaming softmax. Q pre-scaled by
// (1/sqrt(128))*log2(e) at weight-convert time, masked tile peeled.
__global__ __launch_bounds__(256, 2) void k_attn(const unsigned short* __restrict__ qk,
                                                 const unsigned short* __restrict__ vT,
                                                 unsigned short* __restrict__ ctx) {
  __shared__ unsigned short Ks[2][64 * 128];
  __shared__ unsigned short Vs[2][64 * 128];
  const int b = blockIdx.x, h = blockIdx.y, g = h >> 2;
  const int t = threadIdx.x, lane = t & 63, w = t >> 6;
  const int l15 = lane & 15, lq = lane >> 4;

  for (int ph = 0; ph < 2; ++ph) {
    const int qt = ph ? 63 - b : b;
    const int qg = qt * 64 + w * 16 + l15;   // this lane's softmax q-row (global)

    bf16x8 aq[4];                 // Q fragments (B-operand: col=l15, k-chunk by lq)
    {
      const unsigned short* qb =
          qk + (size_t)(qt * 64 + w * 16 + l15) * 3072 + h * 128 + lq * 8;
#pragma unroll
      for (int sl = 0; sl < 4; ++sl) aq[sl] = *(const bf16x8*)(qb + sl * 32);
    }
    f32x4 o[8] = {};
    float lsum = 0.f;

    stage_k(qk, Ks[0], 0, g, t, w);
    stage_v(vT, Vs[0], 0, g, t, w);
    asm volatile("s_waitcnt vmcnt(0)" ::: "memory");
    __builtin_amdgcn_s_barrier();

    auto tile = [&](const unsigned short* Kb, const unsigned short* Vb,
                    int kt, bool maskT) {
      // ---- S^T = K @ Q^T : lane gets P[q=l15][key=nt*16+lq*4+r] ----
      f32x4 st[4] = {};
      __builtin_amdgcn_s_setprio(1);
#pragma unroll
      for (int sl = 0; sl < 4; ++sl)
#pragma unroll
        for (int nt = 0; nt < 4; ++nt) {
          int key = nt * 16 + l15;
          int off = (key * 256 + sl * 64 + lq * 16) ^ ((key & 7) << 4);
          bf16x8 bk = *(const bf16x8*)((const char*)Kb + off);
          st[nt] = __builtin_amdgcn_mfma_f32_16x16x32_bf16(bk, aq[sl], st[nt], 0, 0, 0);
        }
      __builtin_amdgcn_s_setprio(0);

      // ---- streaming softmax, in-register (no max, no cross-lane) ----
      bf16x4 pa[4];
#pragma unroll
      for (int nt = 0; nt < 4; ++nt)
#pragma unroll
        for (int r = 0; r < 4; ++r) {
          float p = __builtin_amdgcn_exp2f(st[nt][r]);   // Q pre-scaled
          if (maskT) {
            int key = kt * 64 + nt * 16 + lq * 4 + r;
            if (key > qg) p = 0.f;
          }
          lsum += p;
          unsigned int u = __builtin_bit_cast(unsigned int, p) + 0x8000u;
          pa[nt][r] = (short)(u >> 16);
        }

      // ---- O += P @ V : A = P from regs, B = V^T b64 reads ----
      __builtin_amdgcn_s_setprio(1);
#pragma unroll
      for (int nt = 0; nt < 4; ++nt)
#pragma unroll
        for (int dt = 0; dt < 8; ++dt) {
          int d = dt * 16 + l15;
          int off = (d * 128 + nt * 32 + lq * 8) ^ ((d & 7) << 4);
          bf16x4 vv = *(const bf16x4*)((const char*)Vb + off);
          o[dt] = mfma16x16x16(pa[nt], vv, o[dt]);
        }
      __builtin_amdgcn_s_setprio(0);
    };

    for (int kt = 0; kt < qt; ++kt) {        // unmasked main loop
      const int cur = kt & 1;
      stage_k(qk, Ks[cur ^ 1], kt + 1, g, t, w);   // prefetch (kt+1 <= qt valid)
      stage_v(vT, Vs[cur ^ 1], kt + 1, g, t, w);
      tile(Ks[cur], Vs[cur], kt, false);
      asm volatile("s_waitcnt vmcnt(0)" ::: "memory");
      __builtin_amdgcn_s_barrier();
    }
    {                                        // peeled masked diagonal tile
      const int cur = qt & 1;
      tile(Ks[cur], Vs[cur], qt, true);
      __builtin_amdgcn_s_barrier();          // protect buffers for next phase
    }

    // ---- epilogue: row-sum reduce (4 lq-slices), normalize, store ----
    float fs = lsum;
    fs += __shfl_xor(fs, 16);
    fs += __shfl_xor(fs, 32);     // lanes l15, +16, +32, +48 all hold row sum
    float invq[4];
#pragma unroll
    for (int r = 0; r < 4; ++r) invq[r] = 1.f / __shfl(fs, lq * 4 + r);
#pragma unroll
    for (int dt = 0; dt < 8; ++dt)
#pragma unroll
      for (int r = 0; r < 4; ++r) {
        int q = qt * 64 + w * 16 + lq * 4 + r;
        int c = h * 128 + dt * 16 + l15;
        ctx[(size_t)q * 2048 + c] = f2b(o[dt][r] * invq[r]);
      }
  }
}

// ---------------- host ----------------
extern "C" void kernel_launch(void* const* d_in, const int* in_sizes, int n_in,
                              void* d_out, int out_size, void* d_ws, size_t ws_size,
                              hipStream_t stream) {
  const float* x    = (const float*)d_in[0];
  const float* cosb = (const float*)d_in[2];
  const float* sinb = (const float*)d_in[3];
  const float* Wq   = (const float*)d_in[4];
  const float* Wk   = (const float*)d_in[5];
  const float* Wv   = (const float*)d_in[6];
  const float* Wo   = (const float*)d_in[7];

  char* p = (char*)d_ws;
  unsigned short* xb   = (unsigned short*)p; p += (size_t)8388608 * 2;   // x bf16
  unsigned short* wqkv = (unsigned short*)p; p += (size_t)6291456 * 2;   // [3072][2048]
  unsigned short* Wob  = (unsigned short*)p; p += (size_t)4194304 * 2;
  unsigned short* qkvb = (unsigned short*)p; p += (size_t)4096 * 3072 * 2;
  unsigned short* vTb  = (unsigned short*)p; p += (size_t)512 * 4096 * 2;
  unsigned short* ctx  = (unsigned short*)p; p += (size_t)4096 * 2048 * 2;
  if (ws_size < (size_t)(p - (char*)d_ws)) return;

  const float SC = 0.12751741f;   // (1/sqrt(128)) * log2(e), folded into Wq

  k_cvt<<<4096, 256, 0, stream>>>(x,  xb, 1.f);
  k_cvt<<<2048, 256, 0, stream>>>(Wq, wqkv,           SC);
  k_cvt<<< 512, 256, 0, stream>>>(Wk, wqkv + 4194304, 1.f);
  k_cvt<<< 512, 256, 0, stream>>>(Wv, wqkv + 5242880, 1.f);
  k_cvt<<<2048, 256, 0, stream>>>(Wo, Wob, 1.f);

  // qkv = x @ [Wq;Wk;Wv]^T  -> [4096][3072] (q:0-2047, k:2048-2559, v:2560-3071)
  k_gemm_bt<0><<<dim3(24, 32), 256, 0, stream>>>(xb, wqkv, qkvb, 2048, 2048, 2048, 3072);

  k_rope<<<2560, 256, 0, stream>>>(qkvb, cosb, sinb);
  k_tr<<<dim3(64, 8), 256, 0, stream>>>(qkvb, vTb);

  k_attn<<<dim3(32, 16), 256, 0, stream>>>(qkvb, vTb, ctx);

  k_gemm_bt<1><<<dim3(16, 32), 256, 0, stream>>>(ctx, Wob, d_out, 2048, 2048, 2048, 2048);
}